// Round 1
// baseline (1535.534 us; speedup 1.0000x reference)
//
#include <hip/hip_runtime.h>
#include <hip/hip_bf16.h>

// Problem constants
#define D_   256
#define K_   1024
#define HW_  1024
#define B_   64
#define N_   65536

// d_out layout (float offsets), in reference return order
#define OFF_ZQ   ((size_t)0)          // 16777216
#define OFF_LOSS ((size_t)16777216)   // 1
#define OFF_IDX  ((size_t)16777217)   // 65536
#define OFF_PERP ((size_t)16842753)   // 1
#define OFF_USED ((size_t)16842754)   // 1024
#define OFF_ENEW ((size_t)16843778)   // 262144
#define OFF_CSN  ((size_t)17105922)   // 1024
#define OFF_EAVG ((size_t)17106946)   // 262144

// EMA weights, bit-matching jnp f32 weak-typed constants
#define DECAY_F 0.99f
#define W_NEW   ((float)(1.0 - 0.99))        // f32(0.010000000000000009)
#define EPS_F   1e-5f
#define KEPS_F  ((float)(1024.0 * 1e-5))

// ws layout (float offsets)
#define WS_E2    0        // 1024
#define WS_CNT   1024     // 1024
#define WS_ESUM  2048     // 262144
#define WS_SMOO  264192   // 1024
#define WS_LOSS  265216   // 1
#define WS_FLOATS 265218

// ---------------------------------------------------------------- e2[k]
__global__ __launch_bounds__(64) void e2_kernel(const float* __restrict__ E,
                                                float* __restrict__ e2g) {
    int k = blockIdx.x;
    int lane = threadIdx.x;  // 64 lanes, 4 d each
    float4 v = *(const float4*)&E[(size_t)k * D_ + lane * 4];
    double s = (double)v.x * v.x + (double)v.y * v.y +
               (double)v.z * v.z + (double)v.w * v.w;
    #pragma unroll
    for (int m = 32; m > 0; m >>= 1) s += __shfl_xor(s, m, 64);
    if (lane == 0) e2g[k] = (float)s;
}

// ------------------------------------------------- argmin over K (f32 GEMM)
// Block: 256 thr (ty=tid>>4 in [0,16), tx=tid&15), tile 128 pts x 128 codes,
// loop kt over K, d-chunks of 32 via LDS. 8x8 micro-tile per thread.
__global__ __launch_bounds__(256) void argmin_kernel(
    const float* __restrict__ z, const float* __restrict__ E,
    const float* __restrict__ e2g, float* __restrict__ out_idx,
    float* __restrict__ counts) {
    __shared__ float Et[32][128];   // Et[d][k]
    __shared__ float Zt[32][128];   // Zt[d][n]
    __shared__ float redm[16][128];
    __shared__ int   reda[16][128];

    const int tid = threadIdx.x;
    const int tx = tid & 15, ty = tid >> 4;
    const int n0 = blockIdx.x * 128;
    const int b  = n0 >> 10;
    const int hw0 = n0 & 1023;
    const float* zb = z + (size_t)b * D_ * HW_;

    float runmin[8], z2c[8];
    int   runarg[8];
    double z2d[8];
    #pragma unroll
    for (int j = 0; j < 8; ++j) { runmin[j] = 3.4e38f; runarg[j] = 0; z2d[j] = 0.0; }

    for (int kt = 0; kt < 8; ++kt) {
        float acc[8][8];
        #pragma unroll
        for (int i = 0; i < 8; ++i)
            #pragma unroll
            for (int j = 0; j < 8; ++j) acc[i][j] = 0.f;

        for (int dc = 0; dc < 8; ++dc) {
            // ---- stage E-tile (transposed) and Z-tile
            #pragma unroll
            for (int l = 0; l < 4; ++l) {
                int t = tid + l * 256;
                int r = t >> 3, c = t & 7;        // E: k-row r, d-col c*4
                float4 v = *(const float4*)&E[(size_t)(kt * 128 + r) * D_ + dc * 32 + c * 4];
                Et[c * 4 + 0][r] = v.x; Et[c * 4 + 1][r] = v.y;
                Et[c * 4 + 2][r] = v.z; Et[c * 4 + 3][r] = v.w;
                int jr = t >> 5, seg = t & 31;    // Z: d-row jr, col seg*4
                float4 w4 = *(const float4*)&zb[(size_t)(dc * 32 + jr) * HW_ + hw0 + seg * 4];
                *(float4*)&Zt[jr][seg * 4] = w4;
            }
            __syncthreads();

            if (kt == 0) {  // accumulate z^2 per column in f64 (once)
                #pragma unroll 8
                for (int d = 0; d < 32; ++d) {
                    #pragma unroll
                    for (int j = 0; j < 8; ++j) {
                        float v = Zt[d][tx * 8 + j];
                        z2d[j] += (double)v * (double)v;
                    }
                }
            }

            #pragma unroll 4
            for (int d = 0; d < 32; ++d) {
                float a[8], bb[8];
                *(float4*)&a[0]  = *(const float4*)&Et[d][ty * 8];
                *(float4*)&a[4]  = *(const float4*)&Et[d][ty * 8 + 4];
                *(float4*)&bb[0] = *(const float4*)&Zt[d][tx * 8];
                *(float4*)&bb[4] = *(const float4*)&Zt[d][tx * 8 + 4];
                #pragma unroll
                for (int i = 0; i < 8; ++i)
                    #pragma unroll
                    for (int j = 0; j < 8; ++j)
                        acc[i][j] = __builtin_fmaf(a[i], bb[j], acc[i][j]);
            }
            __syncthreads();
        }

        if (kt == 0) {
            #pragma unroll
            for (int j = 0; j < 8; ++j) z2c[j] = (float)z2d[j];
        }

        // ---- epilogue: dist = fl((z2 + e2) - fl(2*S)), running min (first-idx ties)
        int kbase = kt * 128 + ty * 8;
        float e2v[8];
        *(float4*)&e2v[0] = *(const float4*)&e2g[kbase];
        *(float4*)&e2v[4] = *(const float4*)&e2g[kbase + 4];
        #pragma unroll
        for (int i = 0; i < 8; ++i) {
            #pragma unroll
            for (int j = 0; j < 8; ++j) {
                float s    = __fadd_rn(z2c[j], e2v[i]);
                float dist = __fsub_rn(s, __fmul_rn(2.0f, acc[i][j]));
                if (dist < runmin[j]) { runmin[j] = dist; runarg[j] = kbase + i; }
            }
        }
    }

    // ---- reduce across ty (16 candidates per column)
    #pragma unroll
    for (int j = 0; j < 8; ++j) {
        redm[ty][tx * 8 + j] = runmin[j];
        reda[ty][tx * 8 + j] = runarg[j];
    }
    __syncthreads();
    if (tid < 128) {
        float best = redm[0][tid]; int ba = reda[0][tid];
        #pragma unroll
        for (int t = 1; t < 16; ++t) {
            float m = redm[t][tid]; int a = reda[t][tid];
            if (m < best || (m == best && a < ba)) { best = m; ba = a; }
        }
        out_idx[n0 + tid] = (float)ba;
        unsafeAtomicAdd(&counts[ba], 1.0f);
    }
}

// -------------------------------------- gather/quantize + loss + embed_sum
// grid: 64 b x 16 d-slices; block 256 thr, each: 4 hw (float4) x 16 d
__global__ __launch_bounds__(256) void quant_kernel(
    const float* __restrict__ z, const float* __restrict__ E,
    const float* __restrict__ idxf, float* __restrict__ zq,
    float* __restrict__ lossacc, float* __restrict__ esum) {
    const int b  = blockIdx.x >> 4;
    const int d0 = (blockIdx.x & 15) * 16;
    const int tid = threadIdx.x;
    const int hw = tid * 4;
    const float* zb = z  + (size_t)b * D_ * HW_;
    float*       qb = zq + (size_t)b * D_ * HW_;

    int idx[4];
    #pragma unroll
    for (int i = 0; i < 4; ++i) idx[i] = (int)idxf[b * HW_ + hw + i];

    float loss = 0.f;
    for (int db = 0; db < 4; ++db) {
        int d = d0 + db * 4;
        float qa[4][4];
        #pragma unroll
        for (int i = 0; i < 4; ++i)
            *(float4*)&qa[i][0] = *(const float4*)&E[(size_t)idx[i] * D_ + d];
        #pragma unroll
        for (int dd = 0; dd < 4; ++dd) {
            float4 z4 = *(const float4*)&zb[(size_t)(d + dd) * HW_ + hw];
            float zv[4] = {z4.x, z4.y, z4.z, z4.w};
            float o[4];
            #pragma unroll
            for (int i = 0; i < 4; ++i) {
                float diff = __fsub_rn(qa[i][dd], zv[i]);   // quantized - z
                float zqv  = __fadd_rn(zv[i], diff);        // z + (q - z)
                o[i] = zqv;
                float l = __fsub_rn(zqv, zv[i]);
                loss = __builtin_fmaf(l, l, loss);
                unsafeAtomicAdd(&esum[(size_t)idx[i] * D_ + d + dd], zv[i]);
            }
            *(float4*)&qb[(size_t)(d + dd) * HW_ + hw] = make_float4(o[0], o[1], o[2], o[3]);
        }
    }

    __shared__ float ls[256];
    ls[tid] = loss;
    __syncthreads();
    for (int s = 128; s > 0; s >>= 1) {
        if (tid < s) ls[tid] += ls[tid + s];
        __syncthreads();
    }
    if (tid == 0) unsafeAtomicAdd(lossacc, ls[0]);
}

// ----------------------------------- finalize scalars / per-code quantities
__global__ __launch_bounds__(1024) void fin1(
    const float* __restrict__ counts, const float* __restrict__ cs_in,
    const float* __restrict__ lossacc, float* __restrict__ out,
    float* __restrict__ smoothed) {
    const int k = threadIdx.x;
    __shared__ float red[1024];

    float c = counts[k];
    float csn = __fadd_rn(__fmul_rn(DECAY_F, cs_in[k]), __fmul_rn(W_NEW, c));
    out[OFF_CSN + k]  = csn;
    out[OFF_USED + k] = (c > 0.f) ? 1.f : 0.f;

    // n = sum(csn)
    red[k] = csn; __syncthreads();
    for (int s = 512; s > 0; s >>= 1) { if (k < s) red[k] += red[k + s]; __syncthreads(); }
    float n_ = red[0]; __syncthreads();

    // total = sum(counts)
    red[k] = c; __syncthreads();
    for (int s = 512; s > 0; s >>= 1) { if (k < s) red[k] += red[k + s]; __syncthreads(); }
    float total = red[0]; __syncthreads();

    // entropy term
    float p = c / total;
    red[k] = p * logf(p + 1e-10f); __syncthreads();
    for (int s = 512; s > 0; s >>= 1) { if (k < s) red[k] += red[k + s]; __syncthreads(); }
    if (k == 0) {
        out[OFF_PERP] = expf(-red[0]);
        out[OFF_LOSS] = lossacc[0] / 16777216.0f;
    }

    smoothed[k] = __fmul_rn(__fdiv_rn(__fadd_rn(csn, EPS_F), __fadd_rn(n_, KEPS_F)), n_);
}

// ------------------------------------------- embedding_avg_new / embedding_new
__global__ __launch_bounds__(256) void fin2(
    const float* __restrict__ eavg_in, const float* __restrict__ esum,
    const float* __restrict__ smoothed, float* __restrict__ out) {
    int e = blockIdx.x * 256 + threadIdx.x;  // 262144
    int k = e >> 8;
    float ean = __fadd_rn(__fmul_rn(DECAY_F, eavg_in[e]), __fmul_rn(W_NEW, esum[e]));
    out[OFF_EAVG + e] = ean;
    out[OFF_ENEW + e] = __fdiv_rn(ean, smoothed[k]);
}

extern "C" void kernel_launch(void* const* d_in, const int* in_sizes, int n_in,
                              void* d_out, int out_size, void* d_ws, size_t ws_size,
                              hipStream_t stream) {
    const float* z    = (const float*)d_in[0];
    const float* E    = (const float*)d_in[1];
    const float* cs   = (const float*)d_in[2];
    const float* eavg = (const float*)d_in[3];
    float* out = (float*)d_out;
    float* wsf = (float*)d_ws;

    hipMemsetAsync(d_ws, 0, WS_FLOATS * sizeof(float), stream);
    e2_kernel<<<K_, 64, 0, stream>>>(E, wsf + WS_E2);
    argmin_kernel<<<N_ / 128, 256, 0, stream>>>(z, E, wsf + WS_E2,
                                                out + OFF_IDX, wsf + WS_CNT);
    quant_kernel<<<B_ * 16, 256, 0, stream>>>(z, E, out + OFF_IDX, out + OFF_ZQ,
                                              wsf + WS_LOSS, wsf + WS_ESUM);
    fin1<<<1, 1024, 0, stream>>>(wsf + WS_CNT, cs, wsf + WS_LOSS, out, wsf + WS_SMOO);
    fin2<<<K_ * D_ / 256, 256, 0, stream>>>(eavg, wsf + WS_ESUM, wsf + WS_SMOO, out);
}

// Round 2
// 878.533 us; speedup vs baseline: 1.7478x; 1.7478x over previous
//
#include <hip/hip_runtime.h>
#include <hip/hip_bf16.h>

// Problem constants
#define D_   256
#define K_   1024
#define HW_  1024
#define B_   64
#define N_   65536

// d_out layout (float offsets), in reference return order
#define OFF_ZQ   ((size_t)0)          // 16777216
#define OFF_LOSS ((size_t)16777216)   // 1
#define OFF_IDX  ((size_t)16777217)   // 65536
#define OFF_PERP ((size_t)16842753)   // 1
#define OFF_USED ((size_t)16842754)   // 1024
#define OFF_ENEW ((size_t)16843778)   // 262144
#define OFF_CSN  ((size_t)17105922)   // 1024
#define OFF_EAVG ((size_t)17106946)   // 262144

#define DECAY_F 0.99f
#define W_NEW   ((float)(1.0 - 0.99))
#define EPS_F   1e-5f
#define KEPS_F  ((float)(1024.0 * 1e-5))

// ws layout (float offsets)
#define WS_E2     0         // 1024 f
#define WS_CNT    1024      // 1024 f
#define WS_LOSS   2048      // 1 f
#define WS_SMOO   2304      // 1024 f
#define WS_ETG    4096      // 262144 f : E transposed [D][K]
#define WS_OFFS   266240    // 1024 i
#define WS_CURS   267264    // 1024 i
#define WS_BUCKET 268288    // 65536 i

// ------------------------------------------------ E[K][D] -> Etg[D][K]
__global__ __launch_bounds__(256) void transpose_kernel(
    const float* __restrict__ E, float* __restrict__ Etg) {
    __shared__ float tile[32][33];
    const int tid = threadIdx.x;
    const int k0 = (blockIdx.x & 31) * 32;
    const int d0 = (blockIdx.x >> 5) * 32;
    {
        int r = tid >> 3, c = (tid & 7) * 4;
        float4 v = *(const float4*)&E[(size_t)(k0 + r) * D_ + d0 + c];
        tile[r][c + 0] = v.x; tile[r][c + 1] = v.y;
        tile[r][c + 2] = v.z; tile[r][c + 3] = v.w;
    }
    __syncthreads();
    {
        int dr = tid >> 3, kc = (tid & 7) * 4;
        float4 o = make_float4(tile[kc + 0][dr], tile[kc + 1][dr],
                               tile[kc + 2][dr], tile[kc + 3][dr]);
        *(float4*)&Etg[(size_t)(d0 + dr) * K_ + k0 + kc] = o;
    }
}

// ---------------------------------------------------------------- e2[k]
__global__ __launch_bounds__(64) void e2_kernel(const float* __restrict__ E,
                                                float* __restrict__ e2g) {
    int k = blockIdx.x;
    int lane = threadIdx.x;
    float4 v = *(const float4*)&E[(size_t)k * D_ + lane * 4];
    double s = (double)v.x * v.x + (double)v.y * v.y +
               (double)v.z * v.z + (double)v.w * v.w;
    #pragma unroll
    for (int m = 32; m > 0; m >>= 1) s += __shfl_xor(s, m, 64);
    if (lane == 0) e2g[k] = (float)s;
}

// ------------------------------------------------- argmin over K (f32 GEMM)
// 256 thr, tile 128 pts x 128 codes. Thread columns spread over bank quads:
// col(j) = tx*4 + (j&3) + 64*(j>>2). Distance arithmetic identical to r1.
__global__ __launch_bounds__(256) void argmin_kernel(
    const float* __restrict__ z, const float* __restrict__ Etg,
    const float* __restrict__ e2g, float* __restrict__ out_idx,
    float* __restrict__ counts) {
    __shared__ float smem[2 * 32 * 128];           // 32 KB
    float (*Et)[128]   = (float(*)[128])smem;
    float (*Zt)[128]   = (float(*)[128])(smem + 32 * 128);
    float (*redm)[128] = (float(*)[128])smem;      // reused after main loop
    int   (*reda)[128] = (int(*)[128])(smem + 16 * 128);

    const int tid = threadIdx.x;
    const int tx = tid & 15, ty = tid >> 4;
    const int n0 = blockIdx.x * 128;
    const int b  = n0 >> 10;
    const int hw0 = n0 & 1023;
    const float* zb = z + (size_t)b * (D_ * HW_);

    float runmin[8], z2c[8];
    int   runarg[8];
    double z2d[8];
    #pragma unroll
    for (int j = 0; j < 8; ++j) { runmin[j] = 3.4e38f; runarg[j] = 0; z2d[j] = 0.0; }

    for (int kt = 0; kt < 8; ++kt) {
        float acc[8][8];
        #pragma unroll
        for (int i = 0; i < 8; ++i)
            #pragma unroll
            for (int j = 0; j < 8; ++j) acc[i][j] = 0.f;

        for (int dc = 0; dc < 8; ++dc) {
            #pragma unroll
            for (int l = 0; l < 4; ++l) {
                int t2 = tid + l * 256;
                int r = t2 >> 5, s = t2 & 31;       // d-row, float4 slot
                float4 ev = *(const float4*)&Etg[(size_t)(dc * 32 + r) * K_ + kt * 128 + s * 4];
                *(float4*)&Et[r][s * 4] = ev;
                float4 zv = *(const float4*)&zb[(size_t)(dc * 32 + r) * HW_ + hw0 + s * 4];
                *(float4*)&Zt[r][s * 4] = zv;
            }
            __syncthreads();

            if (kt == 0) {
                #pragma unroll 8
                for (int d = 0; d < 32; ++d) {
                    #pragma unroll
                    for (int j = 0; j < 8; ++j) {
                        float v = Zt[d][tx * 4 + (j & 3) + 64 * (j >> 2)];
                        z2d[j] += (double)v * (double)v;
                    }
                }
            }

            #pragma unroll 4
            for (int d = 0; d < 32; ++d) {
                float a[8], bb[8];
                *(float4*)&a[0]  = *(const float4*)&Et[d][ty * 8];
                *(float4*)&a[4]  = *(const float4*)&Et[d][ty * 8 + 4];
                *(float4*)&bb[0] = *(const float4*)&Zt[d][tx * 4];
                *(float4*)&bb[4] = *(const float4*)&Zt[d][64 + tx * 4];
                #pragma unroll
                for (int i = 0; i < 8; ++i)
                    #pragma unroll
                    for (int j = 0; j < 8; ++j)
                        acc[i][j] = __builtin_fmaf(a[i], bb[j], acc[i][j]);
            }
            __syncthreads();
        }

        if (kt == 0) {
            #pragma unroll
            for (int j = 0; j < 8; ++j) z2c[j] = (float)z2d[j];
        }

        int kbase = kt * 128 + ty * 8;
        float e2v[8];
        *(float4*)&e2v[0] = *(const float4*)&e2g[kbase];
        *(float4*)&e2v[4] = *(const float4*)&e2g[kbase + 4];
        #pragma unroll
        for (int i = 0; i < 8; ++i) {
            #pragma unroll
            for (int j = 0; j < 8; ++j) {
                float s    = __fadd_rn(z2c[j], e2v[i]);
                float dist = __fsub_rn(s, __fmul_rn(2.0f, acc[i][j]));
                if (dist < runmin[j]) { runmin[j] = dist; runarg[j] = kbase + i; }
            }
        }
    }

    #pragma unroll
    for (int j = 0; j < 8; ++j) {
        int col = tx * 4 + (j & 3) + 64 * (j >> 2);
        redm[ty][col] = runmin[j];
        reda[ty][col] = runarg[j];
    }
    __syncthreads();
    if (tid < 128) {
        float best = redm[0][tid]; int ba = reda[0][tid];
        #pragma unroll
        for (int t = 1; t < 16; ++t) {
            float m = redm[t][tid]; int a = reda[t][tid];
            if (m < best || (m == best && a < ba)) { best = m; ba = a; }
        }
        out_idx[n0 + tid] = (float)ba;
        unsafeAtomicAdd(&counts[ba], 1.0f);
    }
}

// -------------------------------- quantize + zq + loss (pure streaming)
__global__ __launch_bounds__(256) void quant_kernel(
    const float* __restrict__ z, const float* __restrict__ E,
    const float* __restrict__ idxf, float* __restrict__ zq,
    float* __restrict__ lossacc) {
    const int b  = blockIdx.x >> 4;
    const int d0 = (blockIdx.x & 15) * 16;
    const int tid = threadIdx.x;
    const int hw = tid * 4;
    const float* zb = z  + (size_t)b * (D_ * HW_);
    float*       qb = zq + (size_t)b * (D_ * HW_);

    int idx[4];
    #pragma unroll
    for (int i = 0; i < 4; ++i) idx[i] = (int)idxf[b * HW_ + hw + i];

    float loss = 0.f;
    for (int db = 0; db < 4; ++db) {
        int d = d0 + db * 4;
        float qa[4][4];
        #pragma unroll
        for (int i = 0; i < 4; ++i)
            *(float4*)&qa[i][0] = *(const float4*)&E[(size_t)idx[i] * D_ + d];
        #pragma unroll
        for (int dd = 0; dd < 4; ++dd) {
            float4 z4 = *(const float4*)&zb[(size_t)(d + dd) * HW_ + hw];
            float zv[4] = {z4.x, z4.y, z4.z, z4.w};
            float o[4];
            #pragma unroll
            for (int i = 0; i < 4; ++i) {
                float diff = __fsub_rn(qa[i][dd], zv[i]);
                float zqv  = __fadd_rn(zv[i], diff);
                o[i] = zqv;
                float l = __fsub_rn(zqv, zv[i]);
                loss = __builtin_fmaf(l, l, loss);
            }
            *(float4*)&qb[(size_t)(d + dd) * HW_ + hw] = make_float4(o[0], o[1], o[2], o[3]);
        }
    }

    __shared__ float ls[256];
    ls[tid] = loss;
    __syncthreads();
    for (int s = 128; s > 0; s >>= 1) {
        if (tid < s) ls[tid] += ls[tid + s];
        __syncthreads();
    }
    if (tid == 0) unsafeAtomicAdd(lossacc, ls[0]);
}

// ----------------------------------- per-code scalars (no loss here)
__global__ __launch_bounds__(1024) void fin1(
    const float* __restrict__ counts, const float* __restrict__ cs_in,
    float* __restrict__ out, float* __restrict__ smoothed) {
    const int k = threadIdx.x;
    __shared__ float red[1024];

    float c = counts[k];
    float csn = __fadd_rn(__fmul_rn(DECAY_F, cs_in[k]), __fmul_rn(W_NEW, c));
    out[OFF_CSN + k]  = csn;
    out[OFF_USED + k] = (c > 0.f) ? 1.f : 0.f;

    red[k] = csn; __syncthreads();
    for (int s = 512; s > 0; s >>= 1) { if (k < s) red[k] += red[k + s]; __syncthreads(); }
    float n_ = red[0]; __syncthreads();

    red[k] = c; __syncthreads();
    for (int s = 512; s > 0; s >>= 1) { if (k < s) red[k] += red[k + s]; __syncthreads(); }
    float total = red[0]; __syncthreads();

    float p = c / total;
    red[k] = p * logf(p + 1e-10f); __syncthreads();
    for (int s = 512; s > 0; s >>= 1) { if (k < s) red[k] += red[k + s]; __syncthreads(); }
    if (k == 0) out[OFF_PERP] = expf(-red[0]);

    smoothed[k] = __fmul_rn(__fdiv_rn(__fadd_rn(csn, EPS_F), __fadd_rn(n_, KEPS_F)), n_);
}

__global__ void fin_loss(const float* __restrict__ lossacc, float* __restrict__ out) {
    if (threadIdx.x == 0) out[OFF_LOSS] = lossacc[0] / 16777216.0f;
}

// --------------------------- exclusive scan of counts -> offsets, cursor
__global__ __launch_bounds__(1024) void scan_kernel(
    const float* __restrict__ counts, int* __restrict__ offs,
    int* __restrict__ cursor) {
    __shared__ int s[1024];
    const int k = threadIdx.x;
    int c = (int)counts[k];
    s[k] = c; __syncthreads();
    for (int dlt = 1; dlt < 1024; dlt <<= 1) {
        int v = (k >= dlt) ? s[k - dlt] : 0;
        __syncthreads();
        s[k] += v;
        __syncthreads();
    }
    int off = s[k] - c;
    offs[k] = off;
    cursor[k] = off;
}

// -------------------------------------- scatter point ids into buckets
__global__ __launch_bounds__(256) void scatter_kernel(
    const float* __restrict__ idxf, int* __restrict__ cursor,
    int* __restrict__ bucket) {
    int n = blockIdx.x * 256 + threadIdx.x;
    int k = (int)idxf[n];
    int pos = atomicAdd(&cursor[k], 1);
    bucket[pos] = n;
}

// --------------- per-code gather-sum of z + EMA update (esum atomic-free)
__global__ __launch_bounds__(256) void code_update(
    const float* __restrict__ z, const float* __restrict__ eavg_in,
    const float* __restrict__ smoothed, const float* __restrict__ counts,
    const int* __restrict__ offs, const int* __restrict__ bucket,
    float* __restrict__ out) {
    const int k = blockIdx.x;
    const int d = threadIdx.x;
    const int off = offs[k];
    const int cnt = (int)counts[k];

    float acc = 0.f;
    int i = 0;
    for (; i + 4 <= cnt; i += 4) {
        int p0 = bucket[off + i + 0], p1 = bucket[off + i + 1];
        int p2 = bucket[off + i + 2], p3 = bucket[off + i + 3];
        float v0 = z[(size_t)(p0 >> 10) * 262144 + (size_t)d * HW_ + (p0 & 1023)];
        float v1 = z[(size_t)(p1 >> 10) * 262144 + (size_t)d * HW_ + (p1 & 1023)];
        float v2 = z[(size_t)(p2 >> 10) * 262144 + (size_t)d * HW_ + (p2 & 1023)];
        float v3 = z[(size_t)(p3 >> 10) * 262144 + (size_t)d * HW_ + (p3 & 1023)];
        acc += v0; acc += v1; acc += v2; acc += v3;
    }
    for (; i < cnt; ++i) {
        int p = bucket[off + i];
        acc += z[(size_t)(p >> 10) * 262144 + (size_t)d * HW_ + (p & 1023)];
    }

    int e = k * D_ + d;
    float ean = __fadd_rn(__fmul_rn(DECAY_F, eavg_in[e]), __fmul_rn(W_NEW, acc));
    out[OFF_EAVG + e] = ean;
    out[OFF_ENEW + e] = __fdiv_rn(ean, smoothed[k]);
}

extern "C" void kernel_launch(void* const* d_in, const int* in_sizes, int n_in,
                              void* d_out, int out_size, void* d_ws, size_t ws_size,
                              hipStream_t stream) {
    const float* z    = (const float*)d_in[0];
    const float* E    = (const float*)d_in[1];
    const float* cs   = (const float*)d_in[2];
    const float* eavg = (const float*)d_in[3];
    float* out = (float*)d_out;
    float* wsf = (float*)d_ws;
    int*   wsi = (int*)d_ws;

    hipMemsetAsync(d_ws, 0, 12288, stream);   // zero E2 / CNT / LOSS regions

    transpose_kernel<<<256, 256, 0, stream>>>(E, wsf + WS_ETG);
    e2_kernel<<<K_, 64, 0, stream>>>(E, wsf + WS_E2);
    argmin_kernel<<<N_ / 128, 256, 0, stream>>>(z, wsf + WS_ETG, wsf + WS_E2,
                                                out + OFF_IDX, wsf + WS_CNT);
    fin1<<<1, 1024, 0, stream>>>(wsf + WS_CNT, cs, out, wsf + WS_SMOO);
    scan_kernel<<<1, 1024, 0, stream>>>(wsf + WS_CNT, wsi + WS_OFFS, wsi + WS_CURS);
    scatter_kernel<<<N_ / 256, 256, 0, stream>>>(out + OFF_IDX, wsi + WS_CURS,
                                                 wsi + WS_BUCKET);
    quant_kernel<<<B_ * 16, 256, 0, stream>>>(z, E, out + OFF_IDX, out + OFF_ZQ,
                                              wsf + WS_LOSS);
    fin_loss<<<1, 64, 0, stream>>>(wsf + WS_LOSS, out);
    code_update<<<K_, 256, 0, stream>>>(z, eavg, wsf + WS_SMOO, wsf + WS_CNT,
                                        wsi + WS_OFFS, wsi + WS_BUCKET, out);
}

// Round 3
// 655.960 us; speedup vs baseline: 2.3409x; 1.3393x over previous
//
#include <hip/hip_runtime.h>
#include <hip/hip_bf16.h>

#define D_   256
#define K_   1024
#define HW_  1024
#define B_   64
#define N_   65536

#define OFF_ZQ   ((size_t)0)
#define OFF_LOSS ((size_t)16777216)
#define OFF_IDX  ((size_t)16777217)
#define OFF_PERP ((size_t)16842753)
#define OFF_USED ((size_t)16842754)
#define OFF_ENEW ((size_t)16843778)
#define OFF_CSN  ((size_t)17105922)
#define OFF_EAVG ((size_t)17106946)

#define DECAY_F 0.99f
#define W_NEW   ((float)(1.0 - 0.99))
#define EPS_F   1e-5f
#define KEPS_F  ((float)(1024.0 * 1e-5))
#define MARGIN  0.00390625f

// ws layout (float offsets)
#define WS_E2      0        // 1024
#define WS_CNT     1024     // 1024
#define WS_LOSS    2048     // 1
#define WS_FLAGCNT 2052     // 1 (int)
#define WS_SMOO    2304     // 1024
#define WS_OFFS    3328     // 1024 (int)
#define WS_CURS    4352     // 1024 (int)
#define WS_Z2      8192     // 65536
#define WS_BUCKET  73728    // 65536 (int)
#define WS_FLAG    139264   // 65536 (int)

typedef __attribute__((ext_vector_type(8))) short bf16x8;
typedef __attribute__((ext_vector_type(8))) unsigned short u16x8;
typedef __attribute__((ext_vector_type(4))) float f32x4;

static __device__ __forceinline__ float bf2f(unsigned short u) {
    return __uint_as_float(((unsigned int)u) << 16);
}
static __device__ __forceinline__ unsigned short f2bf(float x) {
    unsigned int u = __float_as_uint(x);
    return (unsigned short)((u + 0x7fffu + ((u >> 16) & 1u)) >> 16);
}

// ---------------- prep_z: z[b][d][hw] f32 -> zhiT/zloT [pt][d] bf16 + z2 ----
__global__ __launch_bounds__(256) void prep_z(
    const float* __restrict__ z, unsigned short* __restrict__ zhi,
    unsigned short* __restrict__ zlo, float* __restrict__ z2g) {
    __shared__ float tile[128][68];
    __shared__ double zred[64][4];
    const int tid = threadIdx.x;
    const int b   = blockIdx.x >> 4;
    const int hw0 = (blockIdx.x & 15) * 64;
    const float* zb = z + (size_t)b * (D_ * HW_);

    const int hw = tid >> 2, dq = tid & 3;
    double zacc = 0.0;

    for (int h = 0; h < 2; ++h) {
        // read phase: 128 d-rows x 64 hw
        #pragma unroll
        for (int ch = 0; ch < 8; ++ch) {
            int d = h * 128 + ch * 16 + (tid >> 4);
            int c4 = (tid & 15) * 4;
            float4 v = *(const float4*)&zb[(size_t)d * HW_ + hw0 + c4];
            tile[ch * 16 + (tid >> 4)][c4 + 0] = v.x;
            tile[ch * 16 + (tid >> 4)][c4 + 1] = v.y;
            tile[ch * 16 + (tid >> 4)][c4 + 2] = v.z;
            tile[ch * 16 + (tid >> 4)][c4 + 3] = v.w;
        }
        __syncthreads();
        // write phase: thread owns (hw, 32 d)
        size_t pt = (size_t)b * HW_ + hw0 + hw;
        #pragma unroll
        for (int jb = 0; jb < 4; ++jb) {
            unsigned short hs[8], ls[8];
            #pragma unroll
            for (int e = 0; e < 8; ++e) {
                float v = tile[dq * 32 + jb * 8 + e][hw];
                zacc += (double)v * (double)v;
                unsigned short hh = f2bf(v);
                hs[e] = hh;
                ls[e] = f2bf(v - bf2f(hh));
            }
            size_t dst = pt * D_ + h * 128 + dq * 32 + jb * 8;
            *(u16x8*)&zhi[dst] = *(u16x8*)hs;
            *(u16x8*)&zlo[dst] = *(u16x8*)ls;
        }
        __syncthreads();
    }
    zred[hw][dq] = zacc;
    __syncthreads();
    if (tid < 64) {
        double s = zred[tid][0] + zred[tid][1] + zred[tid][2] + zred[tid][3];
        z2g[b * HW_ + hw0 + tid] = (float)s;
    }
}

// ---------------- prep_e: E[k][d] f32 -> ehi/elo bf16 + e2 (f64) ------------
__global__ __launch_bounds__(64) void prep_e(
    const float* __restrict__ E, unsigned short* __restrict__ ehi,
    unsigned short* __restrict__ elo, float* __restrict__ e2g) {
    int k = blockIdx.x;
    int lane = threadIdx.x;
    float4 v = *(const float4*)&E[(size_t)k * D_ + lane * 4];
    double s = (double)v.x * v.x + (double)v.y * v.y +
               (double)v.z * v.z + (double)v.w * v.w;
    float vv[4] = {v.x, v.y, v.z, v.w};
    ushort4 hs, ls;
    unsigned short* hp = (unsigned short*)&hs;
    unsigned short* lp = (unsigned short*)&ls;
    #pragma unroll
    for (int e = 0; e < 4; ++e) {
        unsigned short hh = f2bf(vv[e]);
        hp[e] = hh;
        lp[e] = f2bf(vv[e] - bf2f(hh));
    }
    *(ushort4*)&ehi[(size_t)k * D_ + lane * 4] = hs;
    *(ushort4*)&elo[(size_t)k * D_ + lane * 4] = ls;
    #pragma unroll
    for (int m = 32; m > 0; m >>= 1) s += __shfl_xor(s, m, 64);
    if (lane == 0) e2g[k] = (float)s;
}

// ---------------- argmin via bf16x3 MFMA + min2 flagging --------------------
__global__ __launch_bounds__(256) void argmin_mfma(
    const unsigned short* __restrict__ zhi, const unsigned short* __restrict__ zlo,
    const unsigned short* __restrict__ ehi, const unsigned short* __restrict__ elo,
    const float* __restrict__ e2g, float* __restrict__ out_idx,
    int* __restrict__ flagged, int* __restrict__ flagcnt) {
    __shared__ unsigned short zl[2][128][40];   // plane, pt, 32 d (+pad) = 20KB
    __shared__ float mred[2][128][3];

    const int tid  = threadIdx.x;
    const int lane = tid & 63;
    const int wid  = tid >> 6;
    const int wr = wid >> 1, wc = wid & 1;     // wave: pts wr*64.., codes wc*64..
    const int x = lane & 15, g = lane >> 4;
    const int pt0 = blockIdx.x * 128;

    const int spt = tid & 127;                  // staging row
    const int spl = tid >> 7;                   // staging plane
    const unsigned short* zsrc = (spl ? zlo : zhi) + (size_t)(pt0 + spt) * D_;

    float m1[16], m2[16];
    int   a1[16];
    #pragma unroll
    for (int s = 0; s < 16; ++s) { m1[s] = 3.4e38f; m2[s] = 3.4e38f; a1[s] = 0; }

    for (int kt = 0; kt < 8; ++kt) {
        f32x4 acc[4][4];
        #pragma unroll
        for (int mf = 0; mf < 4; ++mf)
            #pragma unroll
            for (int nf = 0; nf < 4; ++nf) acc[mf][nf] = (f32x4)0.f;

        for (int dc = 0; dc < 8; ++dc) {
            // stage loads (regs)
            u16x8 s0 = *(const u16x8*)&zsrc[dc * 32 + 0];
            u16x8 s1 = *(const u16x8*)&zsrc[dc * 32 + 8];
            u16x8 s2 = *(const u16x8*)&zsrc[dc * 32 + 16];
            u16x8 s3 = *(const u16x8*)&zsrc[dc * 32 + 24];
            __syncthreads();
            *(u16x8*)&zl[spl][spt][0]  = s0;
            *(u16x8*)&zl[spl][spt][8]  = s1;
            *(u16x8*)&zl[spl][spt][16] = s2;
            *(u16x8*)&zl[spl][spt][24] = s3;
            __syncthreads();

            // B fragments from global (L2-resident E planes)
            bf16x8 bh[4], bl[4];
            #pragma unroll
            for (int nf = 0; nf < 4; ++nf) {
                int code = kt * 128 + wc * 64 + nf * 16 + x;
                size_t base = (size_t)code * D_ + dc * 32 + g * 8;
                bh[nf] = *(const bf16x8*)&ehi[base];
                bl[nf] = *(const bf16x8*)&elo[base];
            }
            // A fragments from LDS
            bf16x8 ah[4], al[4];
            #pragma unroll
            for (int mf = 0; mf < 4; ++mf) {
                int pt = wr * 64 + mf * 16 + x;
                ah[mf] = *(const bf16x8*)&zl[0][pt][g * 8];
                al[mf] = *(const bf16x8*)&zl[1][pt][g * 8];
            }
            #pragma unroll
            for (int mf = 0; mf < 4; ++mf)
                #pragma unroll
                for (int nf = 0; nf < 4; ++nf) {
                    acc[mf][nf] = __builtin_amdgcn_mfma_f32_16x16x32_bf16(ah[mf], bh[nf], acc[mf][nf], 0, 0, 0);
                    acc[mf][nf] = __builtin_amdgcn_mfma_f32_16x16x32_bf16(ah[mf], bl[nf], acc[mf][nf], 0, 0, 0);
                    acc[mf][nf] = __builtin_amdgcn_mfma_f32_16x16x32_bf16(al[mf], bh[nf], acc[mf][nf], 0, 0, 0);
                }
        }

        // epilogue: dist = e2 - 2S ; update (m1, a1, m2) per owned pt
        float e2v[4];
        int   cbase[4];
        #pragma unroll
        for (int nf = 0; nf < 4; ++nf) {
            cbase[nf] = kt * 128 + wc * 64 + nf * 16 + x;
            e2v[nf] = e2g[cbase[nf]];
        }
        #pragma unroll
        for (int mf = 0; mf < 4; ++mf)
            #pragma unroll
            for (int reg = 0; reg < 4; ++reg) {
                int s = mf * 4 + reg;
                #pragma unroll
                for (int nf = 0; nf < 4; ++nf) {
                    float dist = __builtin_fmaf(-2.0f, acc[mf][nf][reg], e2v[nf]);
                    if (dist < m1[s]) { m2[s] = m1[s]; m1[s] = dist; a1[s] = cbase[nf]; }
                    else m2[s] = fminf(m2[s], dist);
                }
            }
    }

    // butterfly across the 16 col-lanes (x) sharing each pt
    #pragma unroll
    for (int mask = 1; mask < 16; mask <<= 1) {
        #pragma unroll
        for (int s = 0; s < 16; ++s) {
            float om1 = __shfl_xor(m1[s], mask, 64);
            int   oa  = __shfl_xor(a1[s], mask, 64);
            float om2 = __shfl_xor(m2[s], mask, 64);
            bool take = (om1 < m1[s]) || (om1 == m1[s] && oa < a1[s]);
            float loser = take ? m1[s] : om1;
            m2[s] = fminf(fminf(m2[s], om2), loser);
            if (take) { m1[s] = om1; a1[s] = oa; }
        }
    }
    if (x < 4) {
        #pragma unroll
        for (int reg = 0; reg < 4; ++reg) {
            int s = x * 4 + reg;
            int ptl = wr * 64 + x * 16 + g * 4 + reg;
            mred[wc][ptl][0] = m1[s];
            mred[wc][ptl][1] = (float)a1[s];
            mred[wc][ptl][2] = m2[s];
        }
    }
    __syncthreads();
    if (tid < 128) {
        float am1 = mred[0][tid][0], bm1 = mred[1][tid][0];
        int   aa  = (int)mred[0][tid][1], ba = (int)mred[1][tid][1];
        float am2 = mred[0][tid][2], bm2 = mred[1][tid][2];
        bool take = (bm1 < am1) || (bm1 == am1 && ba < aa);
        float m1f = take ? bm1 : am1;
        int   a1f = take ? ba : aa;
        float m2f = fminf(fminf(am2, bm2), take ? am1 : bm1);
        out_idx[pt0 + tid] = (float)a1f;
        if (m2f - m1f < MARGIN) {
            int pos = atomicAdd(flagcnt, 1);
            flagged[pos] = pt0 + tid;
        }
    }
}

// ---------------- rescue: exact f32 re-argmin for flagged points ------------
__global__ __launch_bounds__(256) void rescue_kernel(
    const float* __restrict__ z, const float* __restrict__ E,
    const float* __restrict__ e2g, const float* __restrict__ z2g,
    const int* __restrict__ flagged, const int* __restrict__ flagcnt,
    float* __restrict__ out_idx) {
    __shared__ float zs[8][257];
    __shared__ float zz[8];
    __shared__ float redm[256];
    __shared__ int   reda[256];
    const int tid = threadIdx.x;
    const int nflag = flagcnt[0];
    const int nb = (nflag + 7) >> 3;

    for (int bi = blockIdx.x; bi < nb; bi += gridDim.x) {
        int base = bi * 8;
        int cnt = nflag - base; if (cnt > 8) cnt = 8;
        for (int j = 0; j < cnt; ++j) {
            int p = flagged[base + j];
            zs[j][tid] = z[(size_t)(p >> 10) * (D_ * HW_) + (size_t)tid * HW_ + (p & 1023)];
        }
        if (tid < cnt) zz[tid] = z2g[flagged[base + tid]];
        __syncthreads();

        float mj[8], distc[8];
        int   aj[8];
        #pragma unroll
        for (int j = 0; j < 8; ++j) { mj[j] = 3.4e38f; aj[j] = 0; }

        for (int c = 0; c < 4; ++c) {
            int code = tid * 4 + c;
            const float* er = E + (size_t)code * D_;
            float accj[8];
            #pragma unroll
            for (int j = 0; j < 8; ++j) accj[j] = 0.f;
            for (int d = 0; d < D_; ++d) {
                float ev = er[d];
                #pragma unroll
                for (int j = 0; j < 8; ++j)
                    accj[j] = __builtin_fmaf(ev, zs[j][d], accj[j]);
            }
            float e2c = e2g[code];
            #pragma unroll
            for (int j = 0; j < 8; ++j) {
                distc[j] = __fsub_rn(__fadd_rn(zz[j], e2c), __fmul_rn(2.0f, accj[j]));
                if (distc[j] < mj[j]) { mj[j] = distc[j]; aj[j] = code; }
            }
        }
        for (int j = 0; j < cnt; ++j) {
            redm[tid] = mj[j]; reda[tid] = aj[j];
            __syncthreads();
            for (int s = 128; s > 0; s >>= 1) {
                if (tid < s) {
                    float om = redm[tid + s]; int oa = reda[tid + s];
                    if (om < redm[tid] || (om == redm[tid] && oa < reda[tid])) {
                        redm[tid] = om; reda[tid] = oa;
                    }
                }
                __syncthreads();
            }
            if (tid == 0) out_idx[flagged[base + j]] = (float)reda[0];
            __syncthreads();
        }
        __syncthreads();
    }
}

// ---------------- counts from final indices ---------------------------------
__global__ __launch_bounds__(256) void count_kernel(
    const float* __restrict__ idxf, float* __restrict__ counts) {
    int n = blockIdx.x * 256 + threadIdx.x;
    unsafeAtomicAdd(&counts[(int)idxf[n]], 1.0f);
}

// ---------------- quantize + zq + loss --------------------------------------
__global__ __launch_bounds__(256) void quant_kernel(
    const float* __restrict__ z, const float* __restrict__ E,
    const float* __restrict__ idxf, float* __restrict__ zq,
    float* __restrict__ lossacc) {
    const int b  = blockIdx.x >> 4;
    const int d0 = (blockIdx.x & 15) * 16;
    const int tid = threadIdx.x;
    const int hw = tid * 4;
    const float* zb = z  + (size_t)b * (D_ * HW_);
    float*       qb = zq + (size_t)b * (D_ * HW_);

    int idx[4];
    #pragma unroll
    for (int i = 0; i < 4; ++i) idx[i] = (int)idxf[b * HW_ + hw + i];

    float loss = 0.f;
    for (int db = 0; db < 4; ++db) {
        int d = d0 + db * 4;
        float qa[4][4];
        #pragma unroll
        for (int i = 0; i < 4; ++i)
            *(float4*)&qa[i][0] = *(const float4*)&E[(size_t)idx[i] * D_ + d];
        #pragma unroll
        for (int dd = 0; dd < 4; ++dd) {
            float4 z4 = *(const float4*)&zb[(size_t)(d + dd) * HW_ + hw];
            float zv[4] = {z4.x, z4.y, z4.z, z4.w};
            float o[4];
            #pragma unroll
            for (int i = 0; i < 4; ++i) {
                float diff = __fsub_rn(qa[i][dd], zv[i]);
                float zqv  = __fadd_rn(zv[i], diff);
                o[i] = zqv;
                float l = __fsub_rn(zqv, zv[i]);
                loss = __builtin_fmaf(l, l, loss);
            }
            *(float4*)&qb[(size_t)(d + dd) * HW_ + hw] = make_float4(o[0], o[1], o[2], o[3]);
        }
    }
    __shared__ float ls[256];
    ls[tid] = loss;
    __syncthreads();
    for (int s = 128; s > 0; s >>= 1) {
        if (tid < s) ls[tid] += ls[tid + s];
        __syncthreads();
    }
    if (tid == 0) unsafeAtomicAdd(lossacc, ls[0]);
}

// ---------------- per-code scalars ------------------------------------------
__global__ __launch_bounds__(1024) void fin1(
    const float* __restrict__ counts, const float* __restrict__ cs_in,
    float* __restrict__ out, float* __restrict__ smoothed) {
    const int k = threadIdx.x;
    __shared__ float red[1024];
    float c = counts[k];
    float csn = __fadd_rn(__fmul_rn(DECAY_F, cs_in[k]), __fmul_rn(W_NEW, c));
    out[OFF_CSN + k]  = csn;
    out[OFF_USED + k] = (c > 0.f) ? 1.f : 0.f;
    red[k] = csn; __syncthreads();
    for (int s = 512; s > 0; s >>= 1) { if (k < s) red[k] += red[k + s]; __syncthreads(); }
    float n_ = red[0]; __syncthreads();
    red[k] = c; __syncthreads();
    for (int s = 512; s > 0; s >>= 1) { if (k < s) red[k] += red[k + s]; __syncthreads(); }
    float total = red[0]; __syncthreads();
    float p = c / total;
    red[k] = p * logf(p + 1e-10f); __syncthreads();
    for (int s = 512; s > 0; s >>= 1) { if (k < s) red[k] += red[k + s]; __syncthreads(); }
    if (k == 0) out[OFF_PERP] = expf(-red[0]);
    smoothed[k] = __fmul_rn(__fdiv_rn(__fadd_rn(csn, EPS_F), __fadd_rn(n_, KEPS_F)), n_);
}

__global__ void fin_loss(const float* __restrict__ lossacc, float* __restrict__ out) {
    if (threadIdx.x == 0) out[OFF_LOSS] = lossacc[0] / 16777216.0f;
}

// ---------------- scan / scatter --------------------------------------------
__global__ __launch_bounds__(1024) void scan_kernel(
    const float* __restrict__ counts, int* __restrict__ offs,
    int* __restrict__ cursor) {
    __shared__ int s[1024];
    const int k = threadIdx.x;
    int c = (int)counts[k];
    s[k] = c; __syncthreads();
    for (int dlt = 1; dlt < 1024; dlt <<= 1) {
        int v = (k >= dlt) ? s[k - dlt] : 0;
        __syncthreads();
        s[k] += v;
        __syncthreads();
    }
    int off = s[k] - c;
    offs[k] = off;
    cursor[k] = off;
}

__global__ __launch_bounds__(256) void scatter_kernel(
    const float* __restrict__ idxf, int* __restrict__ cursor,
    int* __restrict__ bucket) {
    int n = blockIdx.x * 256 + threadIdx.x;
    int k = (int)idxf[n];
    int pos = atomicAdd(&cursor[k], 1);
    bucket[pos] = n;
}

// ---------------- per-code gather-sum (coalesced via bf16 planes) -----------
__global__ __launch_bounds__(256) void code_update(
    const unsigned short* __restrict__ zhi, const unsigned short* __restrict__ zlo,
    const float* __restrict__ eavg_in, const float* __restrict__ smoothed,
    const float* __restrict__ counts, const int* __restrict__ offs,
    const int* __restrict__ bucket, float* __restrict__ out) {
    const int k = blockIdx.x;
    const int d = threadIdx.x;
    const int off = offs[k];
    const int cnt = (int)counts[k];
    float acc = 0.f;
    for (int i = 0; i < cnt; ++i) {
        int p = bucket[off + i];
        size_t base = (size_t)p * D_ + d;
        acc += bf2f(zhi[base]) + bf2f(zlo[base]);
    }
    int e = k * D_ + d;
    float ean = __fadd_rn(__fmul_rn(DECAY_F, eavg_in[e]), __fmul_rn(W_NEW, acc));
    out[OFF_EAVG + e] = ean;
    out[OFF_ENEW + e] = __fdiv_rn(ean, smoothed[k]);
}

extern "C" void kernel_launch(void* const* d_in, const int* in_sizes, int n_in,
                              void* d_out, int out_size, void* d_ws, size_t ws_size,
                              hipStream_t stream) {
    const float* z    = (const float*)d_in[0];
    const float* E    = (const float*)d_in[1];
    const float* cs   = (const float*)d_in[2];
    const float* eavg = (const float*)d_in[3];
    float* out = (float*)d_out;
    float* wsf = (float*)d_ws;
    int*   wsi = (int*)d_ws;

    // bf16 planes live in output regions that are written later:
    unsigned short* zhiP = (unsigned short*)(out + OFF_ZQ);      // 16.7M ushorts
    unsigned short* zloP = zhiP + (size_t)N_ * D_;               // 16.7M ushorts
    unsigned short* ehiP = (unsigned short*)(out + OFF_ENEW);    // 262144 ushorts
    unsigned short* eloP = ehiP + (size_t)K_ * D_;

    hipMemsetAsync(d_ws, 0, 32768, stream);  // counts, loss, flagcnt

    prep_z<<<1024, 256, 0, stream>>>(z, zhiP, zloP, wsf + WS_Z2);
    prep_e<<<K_, 64, 0, stream>>>(E, ehiP, eloP, wsf + WS_E2);
    argmin_mfma<<<N_ / 128, 256, 0, stream>>>(zhiP, zloP, ehiP, eloP,
                                              wsf + WS_E2, out + OFF_IDX,
                                              wsi + WS_FLAG, wsi + WS_FLAGCNT);
    rescue_kernel<<<256, 256, 0, stream>>>(z, E, wsf + WS_E2, wsf + WS_Z2,
                                           wsi + WS_FLAG, wsi + WS_FLAGCNT,
                                           out + OFF_IDX);
    count_kernel<<<N_ / 256, 256, 0, stream>>>(out + OFF_IDX, wsf + WS_CNT);
    fin1<<<1, 1024, 0, stream>>>(wsf + WS_CNT, cs, out, wsf + WS_SMOO);
    scan_kernel<<<1, 1024, 0, stream>>>(wsf + WS_CNT, wsi + WS_OFFS, wsi + WS_CURS);
    scatter_kernel<<<N_ / 256, 256, 0, stream>>>(out + OFF_IDX, wsi + WS_CURS,
                                                 wsi + WS_BUCKET);
    code_update<<<K_, 256, 0, stream>>>(zhiP, zloP, eavg, wsf + WS_SMOO,
                                        wsf + WS_CNT, wsi + WS_OFFS,
                                        wsi + WS_BUCKET, out);
    quant_kernel<<<B_ * 16, 256, 0, stream>>>(z, E, out + OFF_IDX, out + OFF_ZQ,
                                              wsf + WS_LOSS);
    fin_loss<<<1, 64, 0, stream>>>(wsf + WS_LOSS, out);
}